// Round 1
// baseline (1663.576 us; speedup 1.0000x reference)
//
#include <hip/hip_runtime.h>
#include <hip/hip_bf16.h>

// Problem constants (setup_inputs): B=32, T=1024, D=512, K=3, L=max_len=4096.
#define BB 32
#define TT 1024
#define DD 512
#define LL 4096
#define KDIM 1536  // K*D = 3*512 (im2col reduction dim)

// ---------------------------------------------------------------------------
// Conv-as-GEMM: Y[m, o] = relu( bias[o] + sum_{kk<1536} A[m,kk] * W[kk,o] )
// A[m, kk] = X[b, t + kk/512 - 1, kk%512]  (zero outside [0,T) within batch)
// W flat [K,Din,Dout] row-major == GEMM-B [1536, 512] row-major.
// 128x128 block tile, BK=8, 256 threads, 8x8 micro-tile.
// ---------------------------------------------------------------------------
__global__ __launch_bounds__(256) void conv_gemm_kernel(
    const float* __restrict__ X, const float* __restrict__ W,
    const float* __restrict__ bias, float* __restrict__ Y) {
  __shared__ float As[8][128];   // transposed: As[k][m]
  __shared__ float Bs[8][128];

  const int tid = threadIdx.x;
  const int m0 = blockIdx.x * 128;
  const int n0 = blockIdx.y * 128;

  const int tRow = (tid >> 4) * 8;   // 0..120
  const int tCol = (tid & 15) * 8;   // 0..120

  // A-tile load coords: each thread loads one float4 (128 rows x 8 k = 1024 f)
  const int arow = tid >> 1;           // 0..127
  const int akc  = (tid & 1) * 4;      // 0 or 4
  const int m    = m0 + arow;
  const int t    = m & (TT - 1);       // T=1024 is pow2; tiles never cross batch
  const long xbase = (long)(m - t) * DD;  // b*T*D

  // B-tile load coords: 8 rows x 128 cols = 1024 f, one float4/thread
  const int brow = tid >> 5;           // 0..7
  const int bcol = (tid & 31) * 4;     // 0..124

  float acc[8][8];
#pragma unroll
  for (int i = 0; i < 8; ++i)
#pragma unroll
    for (int j = 0; j < 8; ++j) acc[i][j] = 0.f;

  for (int k0 = 0; k0 < KDIM; k0 += 8) {
    // ---- stage A (im2col with SAME-padding mask) ----
    const int kk  = k0 + akc;      // BK=8 chunks never cross multiples of 512
    const int ksh = kk >> 9;       // 0,1,2  (conv tap)
    const int i0  = kk & 511;
    const int tt  = t + ksh - 1;
    float4 av = make_float4(0.f, 0.f, 0.f, 0.f);
    if (tt >= 0 && tt < TT)
      av = *reinterpret_cast<const float4*>(X + xbase + (long)tt * DD + i0);
    As[akc + 0][arow] = av.x;
    As[akc + 1][arow] = av.y;
    As[akc + 2][arow] = av.z;
    As[akc + 3][arow] = av.w;
    // ---- stage B ----
    float4 bv = *reinterpret_cast<const float4*>(
        W + (long)(k0 + brow) * DD + n0 + bcol);
    *reinterpret_cast<float4*>(&Bs[brow][bcol]) = bv;
    __syncthreads();

#pragma unroll
    for (int k = 0; k < 8; ++k) {
      float4 ra0 = *reinterpret_cast<const float4*>(&As[k][tRow]);
      float4 ra1 = *reinterpret_cast<const float4*>(&As[k][tRow + 4]);
      float4 rb0 = *reinterpret_cast<const float4*>(&Bs[k][tCol]);
      float4 rb1 = *reinterpret_cast<const float4*>(&Bs[k][tCol + 4]);
      float ra[8] = {ra0.x, ra0.y, ra0.z, ra0.w, ra1.x, ra1.y, ra1.z, ra1.w};
      float rb[8] = {rb0.x, rb0.y, rb0.z, rb0.w, rb1.x, rb1.y, rb1.z, rb1.w};
#pragma unroll
      for (int i = 0; i < 8; ++i)
#pragma unroll
        for (int j = 0; j < 8; ++j)
          acc[i][j] = fmaf(ra[i], rb[j], acc[i][j]);
    }
    __syncthreads();
  }

  // epilogue: +bias, ReLU, store
#pragma unroll
  for (int i = 0; i < 8; ++i) {
    const long mm = m0 + tRow + i;
#pragma unroll
    for (int j = 0; j < 8; j += 4) {
      const int n = n0 + tCol + j;
      float4 o;
      o.x = fmaxf(acc[i][j + 0] + bias[n + 0], 0.f);
      o.y = fmaxf(acc[i][j + 1] + bias[n + 1], 0.f);
      o.z = fmaxf(acc[i][j + 2] + bias[n + 2], 0.f);
      o.w = fmaxf(acc[i][j + 3] + bias[n + 3], 0.f);
      *reinterpret_cast<float4*>(Y + mm * DD + n) = o;
    }
  }
}

// ---------------------------------------------------------------------------
// LayerNorm over last dim (512), in place. One wave per row, 4 waves/block.
// ---------------------------------------------------------------------------
__global__ __launch_bounds__(256) void ln_kernel(float* __restrict__ Y,
                                                 const float* __restrict__ g,
                                                 const float* __restrict__ b) {
  const int row  = blockIdx.x * 4 + (threadIdx.x >> 6);
  const int lane = threadIdx.x & 63;
  float* p = Y + (long)row * DD + lane * 8;
  float4 v0 = *reinterpret_cast<const float4*>(p);
  float4 v1 = *reinterpret_cast<const float4*>(p + 4);
  float s  = v0.x + v0.y + v0.z + v0.w + v1.x + v1.y + v1.z + v1.w;
  float sq = v0.x * v0.x + v0.y * v0.y + v0.z * v0.z + v0.w * v0.w +
             v1.x * v1.x + v1.y * v1.y + v1.z * v1.z + v1.w * v1.w;
#pragma unroll
  for (int off = 32; off > 0; off >>= 1) {
    s += __shfl_xor(s, off);
    sq += __shfl_xor(sq, off);
  }
  const float mean = s * (1.f / DD);
  const float var  = sq * (1.f / DD) - mean * mean;
  const float rs   = rsqrtf(var + 1e-5f);
  float4 g0 = *reinterpret_cast<const float4*>(g + lane * 8);
  float4 g1 = *reinterpret_cast<const float4*>(g + lane * 8 + 4);
  float4 b0 = *reinterpret_cast<const float4*>(b + lane * 8);
  float4 b1 = *reinterpret_cast<const float4*>(b + lane * 8 + 4);
  float4 o0, o1;
  o0.x = (v0.x - mean) * rs * g0.x + b0.x;
  o0.y = (v0.y - mean) * rs * g0.y + b0.y;
  o0.z = (v0.z - mean) * rs * g0.z + b0.z;
  o0.w = (v0.w - mean) * rs * g0.w + b0.w;
  o1.x = (v1.x - mean) * rs * g1.x + b1.x;
  o1.y = (v1.y - mean) * rs * g1.y + b1.y;
  o1.z = (v1.z - mean) * rs * g1.z + b1.z;
  o1.w = (v1.w - mean) * rs * g1.w + b1.w;
  *reinterpret_cast<float4*>(p) = o0;
  *reinterpret_cast<float4*>(p + 4) = o1;
}

// ---------------------------------------------------------------------------
// Linear D->1: dpo[m] = dot(H[m,:], w) + b.  One wave per row.
// ---------------------------------------------------------------------------
__global__ __launch_bounds__(256) void linear_kernel(
    const float* __restrict__ H, const float* __restrict__ w,
    const float* __restrict__ b, float* __restrict__ out) {
  const int row  = blockIdx.x * 4 + (threadIdx.x >> 6);
  const int lane = threadIdx.x & 63;
  const float* p = H + (long)row * DD + lane * 8;
  float4 v0 = *reinterpret_cast<const float4*>(p);
  float4 v1 = *reinterpret_cast<const float4*>(p + 4);
  float4 w0 = *reinterpret_cast<const float4*>(w + lane * 8);
  float4 w1 = *reinterpret_cast<const float4*>(w + lane * 8 + 4);
  float s = v0.x * w0.x + v0.y * w0.y + v0.z * w0.z + v0.w * w0.w +
            v1.x * w1.x + v1.y * w1.y + v1.z * w1.z + v1.w * w1.w;
#pragma unroll
  for (int off = 32; off > 0; off >>= 1) s += __shfl_xor(s, off);
  if (lane == 0) out[row] = s + b[0];
}

// ---------------------------------------------------------------------------
// Inclusive cumsum of duration over T=1024, per batch. One block per batch.
// ---------------------------------------------------------------------------
__global__ __launch_bounds__(1024) void cumsum_kernel(
    const int* __restrict__ dur, int* __restrict__ cum) {
  __shared__ int s[TT];
  const int b = blockIdx.x, t = threadIdx.x;
  s[t] = dur[b * TT + t];
  __syncthreads();
  for (int off = 1; off < TT; off <<= 1) {
    int x = (t >= off) ? s[t - off] : 0;
    __syncthreads();
    s[t] += x;
    __syncthreads();
  }
  cum[b * TT + t] = s[t];
}

// ---------------------------------------------------------------------------
// Gather/expand: one block (128 threads) per output frame [b, j].
// idx = first t with cum[t] > j (searchsorted right); zero if j >= total.
// ---------------------------------------------------------------------------
__global__ __launch_bounds__(128) void gather_kernel(
    const float* __restrict__ X, const int* __restrict__ cum,
    float* __restrict__ out) {
  const long blk = blockIdx.x;
  const int b = (int)(blk >> 12);  // L=4096
  const int j = (int)(blk & (LL - 1));
  const int* c = cum + b * TT;
  float4* o = reinterpret_cast<float4*>(out + blk * DD) + threadIdx.x;
  const int total = c[TT - 1];
  if (j >= total) {
    *o = make_float4(0.f, 0.f, 0.f, 0.f);
    return;
  }
  int lo = 0, hi = TT - 1;  // j < total ensures answer < T
  while (lo < hi) {
    const int mid = (lo + hi) >> 1;
    if (c[mid] <= j) lo = mid + 1; else hi = mid;
  }
  const float4* src =
      reinterpret_cast<const float4*>(X + ((long)b * TT + lo) * DD) +
      threadIdx.x;
  *o = *src;
}

// ---------------------------------------------------------------------------
extern "C" void kernel_launch(void* const* d_in, const int* in_sizes, int n_in,
                              void* d_out, int out_size, void* d_ws,
                              size_t ws_size, hipStream_t stream) {
  const float* enc = (const float*)d_in[0];
  const int* dur   = (const int*)d_in[1];
  const float* w1  = (const float*)d_in[2];
  const float* b1  = (const float*)d_in[3];
  const float* g1  = (const float*)d_in[4];
  const float* be1 = (const float*)d_in[5];
  const float* w2  = (const float*)d_in[6];
  const float* b2  = (const float*)d_in[7];
  const float* g2  = (const float*)d_in[8];
  const float* be2 = (const float*)d_in[9];
  const float* lw  = (const float*)d_in[10];
  const float* lb  = (const float*)d_in[11];

  float* out = (float*)d_out;
  float* expanded = out;                       // [B, L, D]
  float* dpo = out + (long)BB * LL * DD;       // [B, T]

  // Scratch: the expanded region (256 MB) is written last by gather_kernel,
  // which reads only enc + cum — so its head is free as conv scratch.
  float* tmpA = expanded;                      // 64 MB: conv1/h1
  float* tmpB = expanded + (long)BB * TT * DD; // 64 MB: conv2/h2
  int* cum = (int*)d_ws;                       // 128 KB

  const int rows = BB * TT;  // 32768
  dim3 gemm_grid(rows / 128, DD / 128);

  // Duration-predictor chain (uses d_out head as scratch)
  conv_gemm_kernel<<<gemm_grid, 256, 0, stream>>>(enc, w1, b1, tmpA);
  ln_kernel<<<rows / 4, 256, 0, stream>>>(tmpA, g1, be1);
  conv_gemm_kernel<<<gemm_grid, 256, 0, stream>>>(tmpA, w2, b2, tmpB);
  ln_kernel<<<rows / 4, 256, 0, stream>>>(tmpB, g2, be2);
  linear_kernel<<<rows / 4, 256, 0, stream>>>(tmpB, lw, lb, dpo);

  // Length regulator (gather overwrites the scratch region)
  cumsum_kernel<<<BB, 1024, 0, stream>>>(dur, cum);
  gather_kernel<<<BB * LL, 128, 0, stream>>>(enc, cum, expanded);
}

// Round 2
// 613.693 us; speedup vs baseline: 2.7108x; 2.7108x over previous
//
#include <hip/hip_runtime.h>
#include <hip/hip_bf16.h>

// Problem constants: B=32, T=1024, D=512, K=3, L=max_len=4096.
#define BB 32
#define TT 1024
#define DD 512
#define LL 4096
#define KDIM 1536        // K*D (im2col reduction dim)
#define TP 1026          // padded T (+1 zero halo row each side)

typedef __attribute__((ext_vector_type(8))) short short8;
typedef __attribute__((ext_vector_type(8))) unsigned short ushort8;
typedef __attribute__((ext_vector_type(4))) float floatx4;

// fp32 -> bf16, round-to-nearest-even (header-independent)
__device__ __forceinline__ unsigned short f2bf(float f) {
  unsigned int u = __builtin_bit_cast(unsigned int, f);
  u += 0x7FFF + ((u >> 16) & 1);
  return (unsigned short)(u >> 16);
}

#define GLOAD_LDS16(g, l)                                          \
  __builtin_amdgcn_global_load_lds(                                \
      (const __attribute__((address_space(1))) void*)(g),          \
      (__attribute__((address_space(3))) void*)(l), 16, 0, 0)

// ---------------------------------------------------------------------------
// Pad+convert: enc fp32 [32][1024][512] -> enc_pad bf16 [32][1026][512]
// with zero halo rows at padded index 0 and 1025. 4 rows per 256-thr block.
// ---------------------------------------------------------------------------
__global__ __launch_bounds__(256) void pad_convert_kernel(
    const float* __restrict__ X, unsigned short* __restrict__ Xp) {
  const int row  = blockIdx.x * 4 + (threadIdx.x >> 6);  // 0..32831
  const int lane = threadIdx.x & 63;
  const int b  = row / TP;
  const int pr = row - b * TP;
  ushort8* o = reinterpret_cast<ushort8*>(Xp + (long)row * DD + lane * 8);
  ushort8 v;
  if (pr == 0 || pr == TP - 1) {
    v = (ushort8)0;
  } else {
    const float* p = X + ((long)(b * TT + pr - 1)) * DD + lane * 8;
    float4 a = *reinterpret_cast<const float4*>(p);
    float4 c = *reinterpret_cast<const float4*>(p + 4);
    v[0] = f2bf(a.x); v[1] = f2bf(a.y); v[2] = f2bf(a.z); v[3] = f2bf(a.w);
    v[4] = f2bf(c.x); v[5] = f2bf(c.y); v[6] = f2bf(c.z); v[7] = f2bf(c.w);
  }
  *o = v;
}

// ---------------------------------------------------------------------------
// Weight transpose+convert: W fp32 [K*D=1536][512] -> Wt bf16 [512][1536].
// One block per output row n; reads are column-strided but W is 3 MB (L2).
// ---------------------------------------------------------------------------
__global__ __launch_bounds__(256) void convert_wt_kernel(
    const float* __restrict__ W, unsigned short* __restrict__ Wt) {
  const int n = blockIdx.x;
  for (int k = threadIdx.x; k < KDIM; k += 256)
    Wt[(long)n * KDIM + k] = f2bf(W[(long)k * DD + n]);
}

// Zero the halo rows of h1_pad (data rows get written by ln1 later).
__global__ __launch_bounds__(256) void zero_halos_kernel(
    unsigned short* __restrict__ Hp) {
  const int b = blockIdx.x >> 1;
  const long r = (long)b * TP + ((blockIdx.x & 1) ? (TP - 1) : 0);
  Hp[r * DD + threadIdx.x] = 0;
  Hp[r * DD + 256 + threadIdx.x] = 0;
}

// ---------------------------------------------------------------------------
// Conv-as-GEMM on matrix cores.
// Y[m,n] = relu(bias[n] + sum_k A[m,k] * W[k,n]),  A = im2col(Xp).
// Xp is the zero-halo padded bf16 input [32][1026][512]: padded row = t + tap.
// 128x128 tile, BK=32, 256 threads = 4 waves (2x2 of 64x64), 16x16x32 MFMA.
// Staging via global_load_lds width=16 (wave-uniform base + lane*16).
// ---------------------------------------------------------------------------
__global__ __launch_bounds__(256) void conv_mfma_kernel(
    const unsigned short* __restrict__ Xp, const unsigned short* __restrict__ Wt,
    const float* __restrict__ bias, float* __restrict__ Y) {
  __shared__ unsigned short As[128 * 32];  // [m][k] 64B rows
  __shared__ unsigned short Bs[128 * 32];  // [n][k] 64B rows

  const int tid  = threadIdx.x;
  const int wid  = tid >> 6;
  const int lane = tid & 63;
  const int m0   = blockIdx.x * 128;
  const int n0   = blockIdx.y * 128;

  const int wm = (wid >> 1) * 64;  // wave row offset in tile
  const int wn = (wid & 1) * 64;   // wave col offset in tile

  // staging coords: shot s covers 64 rows; wave covers 16 rows; lane>>2 = row,
  // lane&3 = 16B chunk within the 64B (32 bf16) row.
  const int srow  = (lane >> 2);
  const int schk  = (lane & 3) * 8;  // shorts

  floatx4 acc[4][4];
#pragma unroll
  for (int i = 0; i < 4; ++i)
#pragma unroll
    for (int j = 0; j < 4; ++j) acc[i][j] = (floatx4){0.f, 0.f, 0.f, 0.f};

  const int frow = lane & 15;       // fragment row within 16
  const int fk   = (lane >> 4) * 8; // fragment k offset (quad*8)

  for (int k0 = 0; k0 < KDIM; k0 += 32) {
    const int tap = k0 >> 9;        // constant across the 32-chunk
    const int c0  = k0 & 511;
#pragma unroll
    for (int s = 0; s < 2; ++s) {
      const int rowA = s * 64 + wid * 16 + srow;
      const int m = m0 + rowA;
      const int b = m >> 10;
      const int t = m & (TT - 1);
      const unsigned short* ga =
          Xp + ((long)(b * TP + t + tap) * DD + c0) + schk;
      GLOAD_LDS16(ga, &As[(s * 64 + wid * 16) * 32]);
      const int n = n0 + rowA;
      const unsigned short* gb = Wt + ((long)n * KDIM + k0) + schk;
      GLOAD_LDS16(gb, &Bs[(s * 64 + wid * 16) * 32]);
    }
    __syncthreads();

    short8 af[4], bf[4];
#pragma unroll
    for (int i = 0; i < 4; ++i)
      af[i] = *reinterpret_cast<const short8*>(
          &As[(wm + i * 16 + frow) * 32 + fk]);
#pragma unroll
    for (int j = 0; j < 4; ++j)
      bf[j] = *reinterpret_cast<const short8*>(
          &Bs[(wn + j * 16 + frow) * 32 + fk]);
#pragma unroll
    for (int i = 0; i < 4; ++i)
#pragma unroll
      for (int j = 0; j < 4; ++j)
        acc[i][j] = __builtin_amdgcn_mfma_f32_16x16x32_bf16(
            af[i], bf[j], acc[i][j], 0, 0, 0);
    __syncthreads();
  }

  // epilogue: C/D layout col=lane&15, row=(lane>>4)*4+reg
  const int quad = lane >> 4;
#pragma unroll
  for (int j = 0; j < 4; ++j) {
    const int col = n0 + wn + j * 16 + frow;
    const float bz = bias[col];
#pragma unroll
    for (int i = 0; i < 4; ++i) {
      const long rbase = (long)(m0 + wm + i * 16 + quad * 4);
#pragma unroll
      for (int r = 0; r < 4; ++r)
        Y[(rbase + r) * DD + col] = fmaxf(acc[i][j][r] + bz, 0.f);
    }
  }
}

// ---------------------------------------------------------------------------
// LayerNorm (512) reading fp32, writing bf16 into padded h1 (row t+1).
// ---------------------------------------------------------------------------
__global__ __launch_bounds__(256) void ln_bf16_kernel(
    const float* __restrict__ Yin, const float* __restrict__ g,
    const float* __restrict__ b, unsigned short* __restrict__ Hp) {
  const int row  = blockIdx.x * 4 + (threadIdx.x >> 6);
  const int lane = threadIdx.x & 63;
  const float* p = Yin + (long)row * DD + lane * 8;
  float4 v0 = *reinterpret_cast<const float4*>(p);
  float4 v1 = *reinterpret_cast<const float4*>(p + 4);
  float s  = v0.x + v0.y + v0.z + v0.w + v1.x + v1.y + v1.z + v1.w;
  float sq = v0.x * v0.x + v0.y * v0.y + v0.z * v0.z + v0.w * v0.w +
             v1.x * v1.x + v1.y * v1.y + v1.z * v1.z + v1.w * v1.w;
#pragma unroll
  for (int off = 32; off > 0; off >>= 1) {
    s += __shfl_xor(s, off);
    sq += __shfl_xor(sq, off);
  }
  const float mean = s * (1.f / DD);
  const float var  = sq * (1.f / DD) - mean * mean;
  const float rs   = rsqrtf(var + 1e-5f);
  float4 g0 = *reinterpret_cast<const float4*>(g + lane * 8);
  float4 g1 = *reinterpret_cast<const float4*>(g + lane * 8 + 4);
  float4 b0 = *reinterpret_cast<const float4*>(b + lane * 8);
  float4 b1 = *reinterpret_cast<const float4*>(b + lane * 8 + 4);
  ushort8 o;
  o[0] = f2bf((v0.x - mean) * rs * g0.x + b0.x);
  o[1] = f2bf((v0.y - mean) * rs * g0.y + b0.y);
  o[2] = f2bf((v0.z - mean) * rs * g0.z + b0.z);
  o[3] = f2bf((v0.w - mean) * rs * g0.w + b0.w);
  o[4] = f2bf((v1.x - mean) * rs * g1.x + b1.x);
  o[5] = f2bf((v1.y - mean) * rs * g1.y + b1.y);
  o[6] = f2bf((v1.z - mean) * rs * g1.z + b1.z);
  o[7] = f2bf((v1.w - mean) * rs * g1.w + b1.w);
  const int bb = row >> 10, t = row & (TT - 1);
  *reinterpret_cast<ushort8*>(Hp + (long)(bb * TP + t + 1) * DD + lane * 8) = o;
}

// LayerNorm in place (fp32), for LN2.
__global__ __launch_bounds__(256) void ln_kernel(float* __restrict__ Y,
                                                 const float* __restrict__ g,
                                                 const float* __restrict__ b) {
  const int row  = blockIdx.x * 4 + (threadIdx.x >> 6);
  const int lane = threadIdx.x & 63;
  float* p = Y + (long)row * DD + lane * 8;
  float4 v0 = *reinterpret_cast<const float4*>(p);
  float4 v1 = *reinterpret_cast<const float4*>(p + 4);
  float s  = v0.x + v0.y + v0.z + v0.w + v1.x + v1.y + v1.z + v1.w;
  float sq = v0.x * v0.x + v0.y * v0.y + v0.z * v0.z + v0.w * v0.w +
             v1.x * v1.x + v1.y * v1.y + v1.z * v1.z + v1.w * v1.w;
#pragma unroll
  for (int off = 32; off > 0; off >>= 1) {
    s += __shfl_xor(s, off);
    sq += __shfl_xor(sq, off);
  }
  const float mean = s * (1.f / DD);
  const float var  = sq * (1.f / DD) - mean * mean;
  const float rs   = rsqrtf(var + 1e-5f);
  float4 g0 = *reinterpret_cast<const float4*>(g + lane * 8);
  float4 g1 = *reinterpret_cast<const float4*>(g + lane * 8 + 4);
  float4 b0 = *reinterpret_cast<const float4*>(b + lane * 8);
  float4 b1 = *reinterpret_cast<const float4*>(b + lane * 8 + 4);
  float4 o0, o1;
  o0.x = (v0.x - mean) * rs * g0.x + b0.x;
  o0.y = (v0.y - mean) * rs * g0.y + b0.y;
  o0.z = (v0.z - mean) * rs * g0.z + b0.z;
  o0.w = (v0.w - mean) * rs * g0.w + b0.w;
  o1.x = (v1.x - mean) * rs * g1.x + b1.x;
  o1.y = (v1.y - mean) * rs * g1.y + b1.y;
  o1.z = (v1.z - mean) * rs * g1.z + b1.z;
  o1.w = (v1.w - mean) * rs * g1.w + b1.w;
  *reinterpret_cast<float4*>(p) = o0;
  *reinterpret_cast<float4*>(p + 4) = o1;
}

// Linear D->1 (fp32). One wave per row.
__global__ __launch_bounds__(256) void linear_kernel(
    const float* __restrict__ H, const float* __restrict__ w,
    const float* __restrict__ b, float* __restrict__ out) {
  const int row  = blockIdx.x * 4 + (threadIdx.x >> 6);
  const int lane = threadIdx.x & 63;
  const float* p = H + (long)row * DD + lane * 8;
  float4 v0 = *reinterpret_cast<const float4*>(p);
  float4 v1 = *reinterpret_cast<const float4*>(p + 4);
  float4 w0 = *reinterpret_cast<const float4*>(w + lane * 8);
  float4 w1 = *reinterpret_cast<const float4*>(w + lane * 8 + 4);
  float s = v0.x * w0.x + v0.y * w0.y + v0.z * w0.z + v0.w * w0.w +
            v1.x * w1.x + v1.y * w1.y + v1.z * w1.z + v1.w * w1.w;
#pragma unroll
  for (int off = 32; off > 0; off >>= 1) s += __shfl_xor(s, off);
  if (lane == 0) out[row] = s + b[0];
}

// Inclusive cumsum over T=1024 per batch.
__global__ __launch_bounds__(1024) void cumsum_kernel(
    const int* __restrict__ dur, int* __restrict__ cum) {
  __shared__ int s[TT];
  const int b = blockIdx.x, t = threadIdx.x;
  s[t] = dur[b * TT + t];
  __syncthreads();
  for (int off = 1; off < TT; off <<= 1) {
    int x = (t >= off) ? s[t - off] : 0;
    __syncthreads();
    s[t] += x;
    __syncthreads();
  }
  cum[b * TT + t] = s[t];
}

// Gather/expand: one 128-thread block per output frame [b, j].
__global__ __launch_bounds__(128) void gather_kernel(
    const float* __restrict__ X, const int* __restrict__ cum,
    float* __restrict__ out) {
  const long blk = blockIdx.x;
  const int b = (int)(blk >> 12);
  const int j = (int)(blk & (LL - 1));
  const int* c = cum + b * TT;
  float4* o = reinterpret_cast<float4*>(out + blk * DD) + threadIdx.x;
  const int total = c[TT - 1];
  if (j >= total) {
    *o = make_float4(0.f, 0.f, 0.f, 0.f);
    return;
  }
  int lo = 0, hi = TT - 1;
  while (lo < hi) {
    const int mid = (lo + hi) >> 1;
    if (c[mid] <= j) lo = mid + 1; else hi = mid;
  }
  const float4* src =
      reinterpret_cast<const float4*>(X + ((long)b * TT + lo) * DD) +
      threadIdx.x;
  *o = *src;
}

// ---------------------------------------------------------------------------
extern "C" void kernel_launch(void* const* d_in, const int* in_sizes, int n_in,
                              void* d_out, int out_size, void* d_ws,
                              size_t ws_size, hipStream_t stream) {
  const float* enc = (const float*)d_in[0];
  const int* dur   = (const int*)d_in[1];
  const float* w1  = (const float*)d_in[2];
  const float* b1  = (const float*)d_in[3];
  const float* g1  = (const float*)d_in[4];
  const float* be1 = (const float*)d_in[5];
  const float* w2  = (const float*)d_in[6];
  const float* b2  = (const float*)d_in[7];
  const float* g2  = (const float*)d_in[8];
  const float* be2 = (const float*)d_in[9];
  const float* lw  = (const float*)d_in[10];
  const float* lb  = (const float*)d_in[11];

  float* out = (float*)d_out;
  float* expanded = out;                       // [B, L, D] = 67,108,864 f
  float* dpo = out + (long)BB * LL * DD;       // [B, T]

  // Scratch carved out of the expanded region (gather writes it last):
  float* tmpA = expanded;                           // 64 MB fp32 conv1 out
  float* tmpB = expanded + 16777216;                // 64 MB fp32 conv2 out
  unsigned short* enc_pad = (unsigned short*)(expanded + 33554432);  // 33.6MB
  unsigned short* h1_pad  = (unsigned short*)(expanded + 41959424);  // 33.6MB
  unsigned short* wt1     = (unsigned short*)(expanded + 50364416);  // 1.5MB
  unsigned short* wt2     = (unsigned short*)(expanded + 50757632);  // 1.5MB
  int* cum = (int*)d_ws;

  const int rows = BB * TT;  // 32768
  dim3 gemm_grid(rows / 128, DD / 128);

  pad_convert_kernel<<<(BB * TP) / 4, 256, 0, stream>>>(enc, enc_pad);
  convert_wt_kernel<<<DD, 256, 0, stream>>>(w1, wt1);
  convert_wt_kernel<<<DD, 256, 0, stream>>>(w2, wt2);
  zero_halos_kernel<<<BB * 2, 256, 0, stream>>>(h1_pad);

  conv_mfma_kernel<<<gemm_grid, 256, 0, stream>>>(enc_pad, wt1, b1, tmpA);
  ln_bf16_kernel<<<rows / 4, 256, 0, stream>>>(tmpA, g1, be1, h1_pad);
  conv_mfma_kernel<<<gemm_grid, 256, 0, stream>>>(h1_pad, wt2, b2, tmpB);
  ln_kernel<<<rows / 4, 256, 0, stream>>>(tmpB, g2, be2);
  linear_kernel<<<rows / 4, 256, 0, stream>>>(tmpB, lw, lb, dpo);

  cumsum_kernel<<<BB, 1024, 0, stream>>>(dur, cum);
  gather_kernel<<<BB * LL, 128, 0, stream>>>(enc, cum, expanded);
}

// Round 3
// 540.490 us; speedup vs baseline: 3.0779x; 1.1354x over previous
//
#include <hip/hip_runtime.h>
#include <hip/hip_bf16.h>

// Problem constants: B=32, T=1024, D=512, K=3, L=max_len=4096.
#define BB 32
#define TT 1024
#define DD 512
#define LL 4096
#define KDIM 1536        // K*D (im2col reduction dim)
#define TP 1026          // padded T (+1 zero halo row each side)

typedef __attribute__((ext_vector_type(8))) short short8;
typedef __attribute__((ext_vector_type(8))) unsigned short ushort8;
typedef __attribute__((ext_vector_type(4))) float floatx4;

__device__ __forceinline__ unsigned short f2bf(float f) {
  unsigned int u = __builtin_bit_cast(unsigned int, f);
  u += 0x7FFF + ((u >> 16) & 1);
  return (unsigned short)(u >> 16);
}

#define GLOAD_LDS16(g, l)                                          \
  __builtin_amdgcn_global_load_lds(                                \
      (const __attribute__((address_space(1))) void*)(g),          \
      (__attribute__((address_space(3))) void*)(l), 16, 0, 0)

// ---------------------------------------------------------------------------
// enc fp32 [32][1024][512] -> bf16 [32][1026][512] with zero halo rows.
// ---------------------------------------------------------------------------
__global__ __launch_bounds__(256) void pad_convert_kernel(
    const float* __restrict__ X, unsigned short* __restrict__ Xp) {
  const int row  = blockIdx.x * 4 + (threadIdx.x >> 6);
  const int lane = threadIdx.x & 63;
  const int b  = row / TP;
  const int pr = row - b * TP;
  ushort8* o = reinterpret_cast<ushort8*>(Xp + (long)row * DD + lane * 8);
  ushort8 v;
  if (pr == 0 || pr == TP - 1) {
    v = (ushort8)0;
  } else {
    const float* p = X + ((long)(b * TT + pr - 1)) * DD + lane * 8;
    float4 a = *reinterpret_cast<const float4*>(p);
    float4 c = *reinterpret_cast<const float4*>(p + 4);
    v[0] = f2bf(a.x); v[1] = f2bf(a.y); v[2] = f2bf(a.z); v[3] = f2bf(a.w);
    v[4] = f2bf(c.x); v[5] = f2bf(c.y); v[6] = f2bf(c.z); v[7] = f2bf(c.w);
  }
  *o = v;
}

// W fp32 [1536][512] -> Wt bf16 [512][1536]
__global__ __launch_bounds__(256) void convert_wt_kernel(
    const float* __restrict__ W, unsigned short* __restrict__ Wt) {
  const int n = blockIdx.x;
  for (int k = threadIdx.x; k < KDIM; k += 256)
    Wt[(long)n * KDIM + k] = f2bf(W[(long)k * DD + n]);
}

__global__ __launch_bounds__(256) void zero_halos_kernel(
    unsigned short* __restrict__ Hp) {
  const int b = blockIdx.x >> 1;
  const long r = (long)b * TP + ((blockIdx.x & 1) ? (TP - 1) : 0);
  Hp[r * DD + threadIdx.x] = 0;
  Hp[r * DD + 256 + threadIdx.x] = 0;
}

// ---------------------------------------------------------------------------
// Fused conv(+bias+ReLU)+LayerNorm[+linear] on matrix cores.
// Tile: 64 rows x 512 (ALL) cols, BK=32, 256 thr = 4 waves, each wave owns
// cols [wid*128, wid*128+128) of all 64 rows -> acc[4][8] 16x16 frags.
// LDS k-chunks XOR-swizzled (chunk ^= row&3) to break 8-way bank aliasing;
// swizzle is applied on the global side of global_load_lds so lane->LDS
// contiguity is preserved.
// MODE 0: out = bf16 LN result into padded h1 (row t+1).
// MODE 1: out = fp32 dpo[m] = dot(LN result, lw) + lb.
// ---------------------------------------------------------------------------
template <int MODE>
__global__ __launch_bounds__(256, 2) void conv_fused_kernel(
    const unsigned short* __restrict__ Xp, const unsigned short* __restrict__ Wt,
    const float* __restrict__ bias, const float* __restrict__ g,
    const float* __restrict__ be, unsigned short* __restrict__ outH,
    const float* __restrict__ lw, const float* __restrict__ lb,
    float* __restrict__ outD) {
  __shared__ unsigned short As[64 * 32];
  __shared__ unsigned short Bs[512 * 32];
  __shared__ float redS[4][64];
  __shared__ float redQ[4][64];

  const int tid  = threadIdx.x;
  const int wid  = tid >> 6;
  const int lane = tid & 63;
  const int m0   = blockIdx.x * 64;

  // staging lane coords (row within a 16-row group, swizzled 16B chunk)
  const int srow   = lane >> 2;
  const int gchunk = (lane & 3) ^ (srow & 3);

  // fragment lane coords
  const int frow    = lane & 15;
  const int quad    = lane >> 4;
  const int rdchunk = quad ^ (frow & 3);

  // A staging: one shot, rows m0 + wid*16 + srow
  const int mA = m0 + wid * 16 + srow;
  const int bA = mA >> 10;
  const int tA = mA & (TT - 1);
  const unsigned short* gA0 =
      Xp + (long)(bA * TP + tA) * DD + gchunk * 8;  // + tap*DD + c0 per iter
  // B staging: 8 shots, rows s*64 + wid*16 + srow
  const int nB = wid * 16 + srow;
  const unsigned short* gB0 = Wt + (long)nB * KDIM + gchunk * 8;

  floatx4 acc[4][8];
#pragma unroll
  for (int i = 0; i < 4; ++i)
#pragma unroll
    for (int j = 0; j < 8; ++j) acc[i][j] = (floatx4){0.f, 0.f, 0.f, 0.f};

  for (int k0 = 0; k0 < KDIM; k0 += 32) {
    const int tap = k0 >> 9;
    const int c0  = k0 & 511;
    GLOAD_LDS16(gA0 + (long)tap * DD + c0, &As[(wid * 16) * 32]);
#pragma unroll
    for (int s = 0; s < 8; ++s)
      GLOAD_LDS16(gB0 + (long)s * 64 * KDIM + k0,
                  &Bs[(s * 64 + wid * 16) * 32]);
    __syncthreads();

    short8 af[4], bfr[8];
#pragma unroll
    for (int i = 0; i < 4; ++i)
      af[i] = *reinterpret_cast<const short8*>(
          &As[(i * 16 + frow) * 32 + rdchunk * 8]);
#pragma unroll
    for (int j = 0; j < 8; ++j)
      bfr[j] = *reinterpret_cast<const short8*>(
          &Bs[(wid * 128 + j * 16 + frow) * 32 + rdchunk * 8]);
#pragma unroll
    for (int i = 0; i < 4; ++i)
#pragma unroll
      for (int j = 0; j < 8; ++j)
        acc[i][j] = __builtin_amdgcn_mfma_f32_16x16x32_bf16(
            af[i], bfr[j], acc[i][j], 0, 0, 0);
    __syncthreads();
  }

  // ---- fused epilogue ----
  // lane's rows: row(i,r) = i*16 + quad*4 + r; cols: c(j) = wid*128 + j*16 + frow
  float bz[8], gv[8], bv[8];
#pragma unroll
  for (int j = 0; j < 8; ++j) {
    const int c = wid * 128 + j * 16 + frow;
    bz[j] = bias[c]; gv[j] = g[c]; bv[j] = be[c];
  }
  float ps[16], pq[16];
#pragma unroll
  for (int i = 0; i < 4; ++i)
#pragma unroll
    for (int r = 0; r < 4; ++r) {
      float s = 0.f, q = 0.f;
#pragma unroll
      for (int j = 0; j < 8; ++j) {
        float v = fmaxf(acc[i][j][r] + bz[j], 0.f);
        acc[i][j][r] = v;
        s += v; q += v * v;
      }
      ps[i * 4 + r] = s; pq[i * 4 + r] = q;
    }
#pragma unroll
  for (int off = 1; off < 16; off <<= 1)
#pragma unroll
    for (int k = 0; k < 16; ++k) {
      ps[k] += __shfl_xor(ps[k], off);
      pq[k] += __shfl_xor(pq[k], off);
    }
  if (frow == 0) {
#pragma unroll
    for (int i = 0; i < 4; ++i)
#pragma unroll
      for (int r = 0; r < 4; ++r) {
        const int row = i * 16 + quad * 4 + r;
        redS[wid][row] = ps[i * 4 + r];
        redQ[wid][row] = pq[i * 4 + r];
      }
  }
  __syncthreads();
  float mean[16], rsd[16];
#pragma unroll
  for (int i = 0; i < 4; ++i)
#pragma unroll
    for (int r = 0; r < 4; ++r) {
      const int row = i * 16 + quad * 4 + r;
      const float s = redS[0][row] + redS[1][row] + redS[2][row] + redS[3][row];
      const float q = redQ[0][row] + redQ[1][row] + redQ[2][row] + redQ[3][row];
      const float mu  = s * (1.f / DD);
      const float var = q * (1.f / DD) - mu * mu;
      mean[i * 4 + r] = mu;
      rsd[i * 4 + r]  = rsqrtf(var + 1e-5f);
    }

  if (MODE == 0) {
#pragma unroll
    for (int i = 0; i < 4; ++i)
#pragma unroll
      for (int r = 0; r < 4; ++r) {
        const int row = i * 16 + quad * 4 + r;
        const int m = m0 + row;
        const int b = m >> 10, t = m & (TT - 1);
        unsigned short* dst = outH + (long)(b * TP + t + 1) * DD;
        const float mu = mean[i * 4 + r], rs = rsd[i * 4 + r];
#pragma unroll
        for (int j = 0; j < 8; ++j)
          dst[wid * 128 + j * 16 + frow] =
              f2bf((acc[i][j][r] - mu) * rs * gv[j] + bv[j]);
      }
  } else {
    float lwv[8];
#pragma unroll
    for (int j = 0; j < 8; ++j) lwv[j] = lw[wid * 128 + j * 16 + frow];
    float pd[16];
#pragma unroll
    for (int i = 0; i < 4; ++i)
#pragma unroll
      for (int r = 0; r < 4; ++r) {
        const float mu = mean[i * 4 + r], rs = rsd[i * 4 + r];
        float d = 0.f;
#pragma unroll
        for (int j = 0; j < 8; ++j)
          d += ((acc[i][j][r] - mu) * rs * gv[j] + bv[j]) * lwv[j];
        pd[i * 4 + r] = d;
      }
#pragma unroll
    for (int off = 1; off < 16; off <<= 1)
#pragma unroll
      for (int k = 0; k < 16; ++k) pd[k] += __shfl_xor(pd[k], off);
    __syncthreads();  // done reading redS/redQ above
    if (frow == 0) {
#pragma unroll
      for (int i = 0; i < 4; ++i)
#pragma unroll
        for (int r = 0; r < 4; ++r)
          redS[wid][i * 16 + quad * 4 + r] = pd[i * 4 + r];
    }
    __syncthreads();
    if (wid == 0 && frow == 0) {
#pragma unroll
      for (int i = 0; i < 4; ++i)
#pragma unroll
        for (int r = 0; r < 4; ++r) {
          const int row = i * 16 + quad * 4 + r;
          outD[m0 + row] = redS[0][row] + redS[1][row] + redS[2][row] +
                           redS[3][row] + lb[0];
        }
    }
  }
}

// Inclusive cumsum over T=1024 per batch.
__global__ __launch_bounds__(1024) void cumsum_kernel(
    const int* __restrict__ dur, int* __restrict__ cum) {
  __shared__ int s[TT];
  const int b = blockIdx.x, t = threadIdx.x;
  s[t] = dur[b * TT + t];
  __syncthreads();
  for (int off = 1; off < TT; off <<= 1) {
    int x = (t >= off) ? s[t - off] : 0;
    __syncthreads();
    s[t] += x;
    __syncthreads();
  }
  cum[b * TT + t] = s[t];
}

// Gather/expand: one 128-thread block per output frame [b, j].
__global__ __launch_bounds__(128) void gather_kernel(
    const float* __restrict__ X, const int* __restrict__ cum,
    float* __restrict__ out) {
  const long blk = blockIdx.x;
  const int b = (int)(blk >> 12);
  const int j = (int)(blk & (LL - 1));
  const int* c = cum + b * TT;
  float4* o = reinterpret_cast<float4*>(out + blk * DD) + threadIdx.x;
  const int total = c[TT - 1];
  if (j >= total) {
    *o = make_float4(0.f, 0.f, 0.f, 0.f);
    return;
  }
  int lo = 0, hi = TT - 1;
  while (lo < hi) {
    const int mid = (lo + hi) >> 1;
    if (c[mid] <= j) lo = mid + 1; else hi = mid;
  }
  const float4* src =
      reinterpret_cast<const float4*>(X + ((long)b * TT + lo) * DD) +
      threadIdx.x;
  *o = *src;
}

// ---------------------------------------------------------------------------
extern "C" void kernel_launch(void* const* d_in, const int* in_sizes, int n_in,
                              void* d_out, int out_size, void* d_ws,
                              size_t ws_size, hipStream_t stream) {
  const float* enc = (const float*)d_in[0];
  const int* dur   = (const int*)d_in[1];
  const float* w1  = (const float*)d_in[2];
  const float* b1  = (const float*)d_in[3];
  const float* g1  = (const float*)d_in[4];
  const float* be1 = (const float*)d_in[5];
  const float* w2  = (const float*)d_in[6];
  const float* b2  = (const float*)d_in[7];
  const float* g2  = (const float*)d_in[8];
  const float* be2 = (const float*)d_in[9];
  const float* lw  = (const float*)d_in[10];
  const float* lb  = (const float*)d_in[11];

  float* out = (float*)d_out;
  float* expanded = out;                       // [B, L, D] = 67,108,864 f
  float* dpo = out + (long)BB * LL * DD;       // [B, T]

  // Scratch carved out of the expanded region (gather writes it last).
  unsigned short* enc_pad = (unsigned short*)(expanded);             // 33.6 MB
  unsigned short* h1_pad  = (unsigned short*)(expanded + 9000000);   // 33.6 MB
  unsigned short* wt1     = (unsigned short*)(expanded + 18000000);  // 1.5 MB
  unsigned short* wt2     = (unsigned short*)(expanded + 18500000);  // 1.5 MB
  int* cum = (int*)d_ws;

  const int rows = BB * TT;  // 32768

  pad_convert_kernel<<<(BB * TP) / 4, 256, 0, stream>>>(enc, enc_pad);
  convert_wt_kernel<<<DD, 256, 0, stream>>>(w1, wt1);
  convert_wt_kernel<<<DD, 256, 0, stream>>>(w2, wt2);
  zero_halos_kernel<<<BB * 2, 256, 0, stream>>>(h1_pad);

  conv_fused_kernel<0><<<rows / 64, 256, 0, stream>>>(
      enc_pad, wt1, b1, g1, be1, h1_pad, nullptr, nullptr, nullptr);
  conv_fused_kernel<1><<<rows / 64, 256, 0, stream>>>(
      h1_pad, wt2, b2, g2, be2, nullptr, lw, lb, dpo);

  cumsum_kernel<<<BB, 1024, 0, stream>>>(dur, cum);
  gather_kernel<<<BB * LL, 128, 0, stream>>>(enc, cum, expanded);
}